// Round 6
// baseline (484.381 us; speedup 1.0000x reference)
//
#include <hip/hip_runtime.h>
#include <stdint.h>

#define NB 4096
#define NT 200
#define NE 64
// attention: 4E=256 -> 64 -> 32 -> 1 ; final MLP: 272 -> 256 -> 128 -> 1
//
// ABI (proven R2-R10): identity order, fp32 floats, int32 ints, FP32 output.
//
// R19: half-key lane pairing (2 t/lane in <=128 VGPRs).
//  - Allocator model (5 data points): arch-VGPR budget == 256/min_waves
//    no matter which knob (launch_bounds or waves_per_eu) declares it.
//    A ~200-reg 2-wave kernel is unreachable -> restructure to fit 128.
//  - Lanes pair up: lane 2m holds e[0:32), lane 2m+1 holds e[32:64) of
//    BOTH keys of the pair's two t's (tA=p, tB=p+128). Keys: 64 regs.
//    Per jj each lane reads only its HALF of weffT/w2 rows: 12 LDS
//    instr/jj/wave vs R13's 24 (2 distinct addrs/instr = free 2-way).
//    Partial dots combined with shfl_xor(,1) (DPP, VALU pipe).
//  - Regs ~120 <= 128 budget -> no spill; 512/125 -> 4 waves/SIMD HW
//    occupancy (16 waves/CU). LDS-pipe floor ~50K instr/CU ~= 195us.
//  - din_mlp: unchanged (MR=4, transposed LDS, unroll-8).

// compile-time component access into a float4[] register array
#define C4(v, i) (((i)&3)==0 ? v[(i)>>2].x : ((i)&3)==1 ? v[(i)>>2].y : \
                  ((i)&3)==2 ? v[(i)>>2].z : v[(i)>>2].w)

// butterfly over the 32 same-half lanes (g = lane>>1), 32 elems -> elem g
#define BFH(S)                                                             \
    {                                                                      \
        const bool hi = (g & (S)) != 0;                                    \
        _Pragma("unroll")                                                  \
        for (int i = 0; i < (S); ++i) {                                    \
            const float snd = hi ? C4(kA, i) : C4(kA, i + (S));            \
            const float rec = __shfl_xor(snd, 2 * (S), 64);                \
            C4(kA, i) = (hi ? C4(kA, i + (S)) : C4(kA, i)) + rec;          \
        }                                                                  \
    }

struct __align__(16) SmemA {
    float weffT[64 * 72];   // [j][e], e padded 64->72 (288B rows, 16B-aligned)
    float w2[64 * 32];      // [j][o]
    float q[64];
    float biasj[64];
    float b2[32];
    float wo[32];
    float ip[4 * 64];       // bias partials, later interest partials
    float red_a[4];
    float red_b[4];
};                           // 28448 B -> 4 blocks/CU (reg-capped anyway)

__global__ __launch_bounds__(256)
__attribute__((amdgpu_waves_per_eu(2, 4)))
void din_attn(const int* __restrict__ target_item,
              const int* __restrict__ history_items,
              const int* __restrict__ history_mask,
              const int* __restrict__ sparse_features,
              const float* __restrict__ dense_features,
              const float* __restrict__ item_table,
              const float* __restrict__ user_table,
              const float* __restrict__ ctx_table,
              const float* __restrict__ att_w1,
              const float* __restrict__ att_b1,
              const float* __restrict__ att_w2,
              const float* __restrict__ att_b2,
              const float* __restrict__ att_wo,
              const float* __restrict__ att_bo,
              float* __restrict__ mlp_in)   // [NB][272]
{
    __shared__ SmemA sm;

    const int b    = blockIdx.x;
    const int tid  = threadIdx.x;    // 0..255
    const int j    = tid & 63;       // lane in wave
    const int wv   = tid >> 6;       // 0..3
    const int half = tid & 1;        // 0: e[0,32), 1: e[32,64)
    const int g    = j >> 1;         // pair index in wave, 0..31
    const int p    = tid >> 1;       // pair index in block, 0..127
    const int tA   = p;              // < 200 always
    const int tB   = p + 128;
    const bool actB = (tB < NT);

    // ---- issue own half-key loads FIRST (registers; overlap staging) ----
    const int hrA = history_items[(size_t)b * NT + tA];
    const int hrB = history_items[(size_t)b * NT + (actB ? tB : 0)];
    float4 kA[8], kB[8];
    {
        const float4* rpA = (const float4*)(item_table + (size_t)hrA * NE) + half * 8;
        const float4* rpB = (const float4*)(item_table + (size_t)hrB * NE) + half * 8;
#pragma unroll
        for (int i = 0; i < 8; ++i) { kA[i] = rpA[i]; kB[i] = rpB[i]; }
    }

    // ---- stage small shared data ----------------------------------------
    if (tid < NE) sm.q[tid] = item_table[(size_t)target_item[b] * NE + tid];
    for (int i = tid; i < 512; i += 256)
        ((float4*)sm.w2)[i] = ((const float4*)att_w2)[i];
    if (tid < 32) { sm.b2[tid] = att_b2[tid]; sm.wo[tid] = att_wo[tid]; }
    const float bo = att_bo[0];
    __syncthreads();

    // ---- W_eff^T[j][e] + bias partials (thread = (wv, j), 16 e's) -------
    // attn_in = [k, q, k-q, k*q] @ w1 factorizes (q row-constant):
    // h1[j] = relu( sum_e k_e*(w1[e,j]+w1[128+e,j]+q_e*w1[192+e,j])
    //              + b1[j] + sum_e q_e*(w1[64+e,j]-w1[128+e,j]) )
    {
        float pb = 0.f;
        for (int e = wv; e < NE; e += 4) {
            const float qe = sm.q[e];
            const float A  = att_w1[(size_t)(e)       * NE + j];
            const float Bv = att_w1[(size_t)(64 + e)  * NE + j];
            const float C  = att_w1[(size_t)(128 + e) * NE + j];
            const float D  = att_w1[(size_t)(192 + e) * NE + j];
            sm.weffT[j * 72 + e] = A + C + qe * D;
            pb += qe * (Bv - C);
        }
        sm.ip[wv * 64 + j] = pb;
    }
    __syncthreads();
    if (tid < NE)
        sm.biasj[tid] = att_b1[tid] + sm.ip[tid] + sm.ip[64 + tid] +
                        sm.ip[128 + tid] + sm.ip[192 + tid];
    __syncthreads();

    // ---- main loop: each lane does its e-half of both t's ---------------
    float h2A[16], h2B[16];
#pragma unroll
    for (int o = 0; o < 16; ++o) { h2A[o] = 0.f; h2B[o] = 0.f; }

#pragma unroll 2
    for (int jj = 0; jj < 64; ++jj) {
        const float4* wrow =
            (const float4*)(sm.weffT + jj * 72 + (half << 5));   // own half
        float a0 = 0.f, a1 = 0.f, a2 = 0.f, a3 = 0.f;
        float b0 = 0.f, b1v = 0.f, b2v = 0.f, b3 = 0.f;
#pragma unroll
        for (int gi = 0; gi < 8; gi += 4) {
            const float4 w0 = wrow[gi + 0];
            const float4 w1 = wrow[gi + 1];
            const float4 w2v = wrow[gi + 2];
            const float4 w3 = wrow[gi + 3];
            a0 += w0.x * kA[gi + 0].x; b0 += w0.x * kB[gi + 0].x;
            a0 += w0.y * kA[gi + 0].y; b0 += w0.y * kB[gi + 0].y;
            a0 += w0.z * kA[gi + 0].z; b0 += w0.z * kB[gi + 0].z;
            a0 += w0.w * kA[gi + 0].w; b0 += w0.w * kB[gi + 0].w;
            a1 += w1.x * kA[gi + 1].x; b1v += w1.x * kB[gi + 1].x;
            a1 += w1.y * kA[gi + 1].y; b1v += w1.y * kB[gi + 1].y;
            a1 += w1.z * kA[gi + 1].z; b1v += w1.z * kB[gi + 1].z;
            a1 += w1.w * kA[gi + 1].w; b1v += w1.w * kB[gi + 1].w;
            a2 += w2v.x * kA[gi + 2].x; b2v += w2v.x * kB[gi + 2].x;
            a2 += w2v.y * kA[gi + 2].y; b2v += w2v.y * kB[gi + 2].y;
            a2 += w2v.z * kA[gi + 2].z; b2v += w2v.z * kB[gi + 2].z;
            a2 += w2v.w * kA[gi + 2].w; b2v += w2v.w * kB[gi + 2].w;
            a3 += w3.x * kA[gi + 3].x; b3 += w3.x * kB[gi + 3].x;
            a3 += w3.y * kA[gi + 3].y; b3 += w3.y * kB[gi + 3].y;
            a3 += w3.z * kA[gi + 3].z; b3 += w3.z * kB[gi + 3].z;
            a3 += w3.w * kA[gi + 3].w; b3 += w3.w * kB[gi + 3].w;
        }
        float aA = (a0 + a1) + (a2 + a3);
        float aB = (b0 + b1v) + (b2v + b3);
        // combine halves within the pair (xor 1 -> quad-perm DPP, VALU)
        aA += __shfl_xor(aA, 1, 64);
        aB += __shfl_xor(aB, 1, 64);
        const float bias = sm.biasj[jj];
        const float h1A = fmaxf(aA + bias, 0.f);
        const float h1B = fmaxf(aB + bias, 0.f);

        const float4* w2row =
            (const float4*)(sm.w2 + jj * 32) + (half << 2);      // own half
#pragma unroll
        for (int o4 = 0; o4 < 4; ++o4) {
            const float4 ww = w2row[o4];
            h2A[4 * o4 + 0] += h1A * ww.x;  h2B[4 * o4 + 0] += h1B * ww.x;
            h2A[4 * o4 + 1] += h1A * ww.y;  h2B[4 * o4 + 1] += h1B * ww.y;
            h2A[4 * o4 + 2] += h1A * ww.z;  h2B[4 * o4 + 2] += h1B * ww.z;
            h2A[4 * o4 + 3] += h1A * ww.w;  h2B[4 * o4 + 3] += h1B * ww.w;
        }
    }

    // ---- L3 scores (each lane: own 16-o half, then pair-combine) --------
    float sA = 0.f, sB = 0.f;
#pragma unroll
    for (int o = 0; o < 16; ++o) {
        const float bb  = sm.b2[half * 16 + o];
        const float wwo = sm.wo[half * 16 + o];
        sA += fmaxf(h2A[o] + bb, 0.f) * wwo;
        sB += fmaxf(h2B[o] + bb, 0.f) * wwo;
    }
    sA += __shfl_xor(sA, 1, 64);
    sB += __shfl_xor(sB, 1, 64);
    const float scrA = sA + bo;
    const float scrB = sB + bo;
    const int mkA = history_mask[(size_t)b * NT + tA];
    const int mkB = actB ? history_mask[(size_t)b * NT + tB] : 0;
    const float vA = (mkA != 0) ? scrA : -1e9f;
    const float vB = actB ? ((mkB != 0) ? scrB : -1e9f) : -INFINITY;
    // even lane represents tA, odd lane tB -> each t counted exactly once
    const float v = half ? vB : vA;

    // ---- softmax over 256 slots (4-wave reduce) -------------------------
    float m = v;
#pragma unroll
    for (int s = 32; s; s >>= 1) m = fmaxf(m, __shfl_xor(m, s));
    if (j == 0) sm.red_a[wv] = m;
    __syncthreads();
    const float mx = fmaxf(fmaxf(sm.red_a[0], sm.red_a[1]),
                           fmaxf(sm.red_a[2], sm.red_a[3]));
    const float ex = __expf(v - mx);   // -inf -> 0
    float ssum = ex;
#pragma unroll
    for (int s = 32; s; s >>= 1) ssum += __shfl_xor(ssum, s);
    if (j == 0) sm.red_b[wv] = ssum;
    __syncthreads();
    const float total = sm.red_b[0] + sm.red_b[1] + sm.red_b[2] + sm.red_b[3];
    const float w = ex / total;
    const float wOther = __shfl_xor(w, 1, 64);
    const float wA = half ? wOther : w;
    const float wB = half ? w : wOther;

    // ---- interest: own e-half of both t's, butterfly over 32 pairs ------
#pragma unroll
    for (int i = 0; i < 32; ++i)
        C4(kA, i) = C4(kA, i) * wA + C4(kB, i) * wB;
    BFH(16)
    BFH(8)
    BFH(4)
    BFH(2)
    BFH(1)
    // lane now holds this wave's partial interest for e = half*32 + g
    sm.ip[wv * 64 + half * 32 + g] = kA[0].x;
    __syncthreads();

    // ---- assemble mlp_in row [user, ctx, q, interest, dense] ------------
    float* row = mlp_in + (size_t)b * 272;
    if (tid < NE) {
        const float inter = sm.ip[tid] + sm.ip[64 + tid] +
                            sm.ip[128 + tid] + sm.ip[192 + tid];
        row[0 + tid]   = user_table[(size_t)sparse_features[b * 2 + 0] * NE + tid];
        row[64 + tid]  = ctx_table[(size_t)sparse_features[b * 2 + 1] * NE + tid];
        row[128 + tid] = sm.q[tid];
        row[192 + tid] = inter;
    } else if (tid >= 64 && tid < 80) {
        row[256 + (tid - 64)] = dense_features[(size_t)b * 16 + (tid - 64)];
    }
}

// ---------------------------------------------------------------------------
// Kernel 2: final MLP 272 -> 256 -> 128 -> 1, 4 rows/block (grid 1024,
// 4 blocks/CU) with transposed LDS activations (broadcast b128 reads) and
// unroll-8 load pipelining.
// ---------------------------------------------------------------------------
#define MR 4
__global__ __launch_bounds__(256)
void din_mlp(const float* __restrict__ mlp_in,
             const float* __restrict__ w1,
             const float* __restrict__ b1,
             const float* __restrict__ w2,
             const float* __restrict__ b2,
             const float* __restrict__ ow,
             const float* __restrict__ ob,
             float* __restrict__ out)
{
    __shared__ float inT[272 * MR];     // [k][r]
    __shared__ float h1T[256 * MR];     // [k][r]
    __shared__ float p2[2 * MR * 128];
    __shared__ float h2_lds[MR * 128];

    const int b0  = blockIdx.x * MR;
    const int tid = threadIdx.x;

    // stage transposed: coalesced global read, scattered LDS write
    for (int i = tid; i < MR * 272; i += 256) {
        const int r = i / 272, k = i - 272 * r;
        inT[k * MR + r] = mlp_in[(size_t)b0 * 272 + i];
    }
    __syncthreads();

    // layer 1: 272 -> 256 (thread = col, MR rows via 1 b128 broadcast/k)
    {
        const float bias = b1[tid];
        float a0 = bias, a1 = bias, a2 = bias, a3 = bias;
        const float4* iT = (const float4*)inT;
#pragma unroll 8
        for (int k = 0; k < 272; ++k) {
            const float wv = w1[(size_t)k * 256 + tid];
            const float4 iv = iT[k];
            a0 += iv.x * wv; a1 += iv.y * wv;
            a2 += iv.z * wv; a3 += iv.w * wv;
        }
        float4 o;
        o.x = fmaxf(a0, 0.f); o.y = fmaxf(a1, 0.f);
        o.z = fmaxf(a2, 0.f); o.w = fmaxf(a3, 0.f);
        ((float4*)h1T)[tid] = o;        // h1T[k=tid][r] contiguous
    }
    __syncthreads();

    // layer 2: 256 -> 128, split-K over two half-blocks
    {
        const int o = tid & 127, half = tid >> 7;
        float c0 = 0.f, c1 = 0.f, c2 = 0.f, c3 = 0.f;
        const float4* hT = (const float4*)h1T;
#pragma unroll 8
        for (int kk = 0; kk < 128; ++kk) {
            const int k = half * 128 + kk;
            const float wv = w2[(size_t)k * 128 + o];
            const float4 hv = hT[k];
            c0 += hv.x * wv; c1 += hv.y * wv;
            c2 += hv.z * wv; c3 += hv.w * wv;
        }
        p2[(half * MR + 0) * 128 + o] = c0;
        p2[(half * MR + 1) * 128 + o] = c1;
        p2[(half * MR + 2) * 128 + o] = c2;
        p2[(half * MR + 3) * 128 + o] = c3;
    }
    __syncthreads();
    if (tid < 128) {
        const float bias = b2[tid];
#pragma unroll
        for (int r = 0; r < MR; ++r)
            h2_lds[r * 128 + tid] =
                fmaxf(p2[r * 128 + tid] + p2[(MR + r) * 128 + tid] + bias, 0.f);
    }
    __syncthreads();

    // layer 3: 128 -> 1 (16 lanes per row)
    if (tid < 16 * MR) {
        const int r = tid >> 4, l = tid & 15;
        float a = 0.f;
#pragma unroll
        for (int kk = 0; kk < 8; ++kk) {
            const int k = l * 8 + kk;
            a += h2_lds[r * 128 + k] * ow[k];
        }
        a += __shfl_xor(a, 8, 16);
        a += __shfl_xor(a, 4, 16);
        a += __shfl_xor(a, 2, 16);
        a += __shfl_xor(a, 1, 16);
        if (l == 0) out[b0 + r] = a + ob[0];
    }
}

// ---------------------------------------------------------------------------
extern "C" void kernel_launch(void* const* d_in, const int* in_sizes, int n_in,
                              void* d_out, int out_size, void* d_ws, size_t ws_size,
                              hipStream_t stream)
{
    float* mlp_in = (float*)d_ws;   // 4096*272*4 = 4.46 MB

    din_attn<<<NB, 256, 0, stream>>>(
        (const int*)d_in[0],      // target_item
        (const int*)d_in[1],      // history_items
        (const int*)d_in[2],      // history_mask
        (const int*)d_in[3],      // sparse_features
        (const float*)d_in[4],    // dense_features
        (const float*)d_in[5],    // item_table
        (const float*)d_in[6],    // user_table
        (const float*)d_in[7],    // ctx_table
        (const float*)d_in[8],  (const float*)d_in[9],   // att_w1, att_b1
        (const float*)d_in[10], (const float*)d_in[11],  // att_w2, att_b2
        (const float*)d_in[12], (const float*)d_in[13],  // att_wo, att_bo
        mlp_in);

    din_mlp<<<NB / MR, 256, 0, stream>>>(
        mlp_in,
        (const float*)d_in[14], (const float*)d_in[15],  // mlp_w1, mlp_b1
        (const float*)d_in[16], (const float*)d_in[17],  // mlp_w2, mlp_b2
        (const float*)d_in[18], (const float*)d_in[19],  // out_w, out_b
        (float*)d_out);
}

// Round 7
// 324.245 us; speedup vs baseline: 1.4939x; 1.4939x over previous
//
#include <hip/hip_runtime.h>
#include <stdint.h>

#define NB 4096
#define NT 200
#define NE 64
// attention: 4E=256 -> 64 -> 32 -> 1 ; final MLP: 272 -> 256 -> 128 -> 1
//
// ABI (proven R2-R10): identity order, fp32 floats, int32 ints, FP32 output.
//
// R20: R19 minus AGPR churn (fit the 128 arch-VGPR budget for real).
//  - R19 post-mortem: spill gone (WRITE 4.3MB) but VALUBusy 67% = 3x the
//    FMA model. Live set ~140 (unroll-2 wrow prefetch) > 128 arch budget
//    -> compiler AGPR'd hot accumulators; every use = accvgpr mov. LDS
//    really did halve; the win was eaten by churn.
//  - Now: (1) no jj unroll; (2) prefetch only 2 float4 of weff / 1 of w2
//    at a time (transients ~12 regs, live ~116 < 128); (3) pair-combine
//    via quad-perm DPP (VALU pipe) instead of __shfl_xor -> ds_swizzle
//    (LDS pipe): 13 LDS instr/jj/wave, none wasted.
//  - Model: LDS 53K instr/CU x ~9cyc ~= 200us (bound); VALU ~90us hidden.
//  - din_mlp: unchanged (MR=4, transposed LDS, unroll-8, ~89us).

// compile-time component access into a float4[] register array
#define C4(v, i) (((i)&3)==0 ? v[(i)>>2].x : ((i)&3)==1 ? v[(i)>>2].y : \
                  ((i)&3)==2 ? v[(i)>>2].z : v[(i)>>2].w)

// pair-swap (lane xor 1) on the VALU pipe: quad_perm [1,0,3,2] = 0xB1
__device__ __forceinline__ float dpp_xor1(float x)
{
    return __int_as_float(__builtin_amdgcn_update_dpp(
        0, __float_as_int(x), 0xB1, 0xF, 0xF, true));
}

// butterfly over the 32 same-half lanes (g = lane>>1), 32 elems -> elem g
#define BFH(S)                                                             \
    {                                                                      \
        const bool hi = (g & (S)) != 0;                                    \
        _Pragma("unroll")                                                  \
        for (int i = 0; i < (S); ++i) {                                    \
            const float snd = hi ? C4(kA, i) : C4(kA, i + (S));            \
            const float rec = __shfl_xor(snd, 2 * (S), 64);                \
            C4(kA, i) = (hi ? C4(kA, i + (S)) : C4(kA, i)) + rec;          \
        }                                                                  \
    }

struct __align__(16) SmemA {
    float weffT[64 * 72];   // [j][e], e padded 64->72 (288B rows, 16B-aligned)
    float w2[64 * 32];      // [j][o]
    float q[64];
    float biasj[64];
    float b2[32];
    float wo[32];
    float ip[4 * 64];       // bias partials, later interest partials
    float red_a[4];
    float red_b[4];
};                           // 28448 B

__global__ __launch_bounds__(256)
__attribute__((amdgpu_waves_per_eu(2, 4)))
void din_attn(const int* __restrict__ target_item,
              const int* __restrict__ history_items,
              const int* __restrict__ history_mask,
              const int* __restrict__ sparse_features,
              const float* __restrict__ dense_features,
              const float* __restrict__ item_table,
              const float* __restrict__ user_table,
              const float* __restrict__ ctx_table,
              const float* __restrict__ att_w1,
              const float* __restrict__ att_b1,
              const float* __restrict__ att_w2,
              const float* __restrict__ att_b2,
              const float* __restrict__ att_wo,
              const float* __restrict__ att_bo,
              float* __restrict__ mlp_in)   // [NB][272]
{
    __shared__ SmemA sm;

    const int b    = blockIdx.x;
    const int tid  = threadIdx.x;    // 0..255
    const int j    = tid & 63;       // lane in wave
    const int wv   = tid >> 6;       // 0..3
    const int half = tid & 1;        // 0: e[0,32), 1: e[32,64)
    const int g    = j >> 1;         // pair index in wave, 0..31
    const int p    = tid >> 1;       // pair index in block, 0..127
    const int tA   = p;              // < 200 always
    const int tB   = p + 128;
    const bool actB = (tB < NT);

    // ---- issue own half-key loads FIRST (registers; overlap staging) ----
    const int hrA = history_items[(size_t)b * NT + tA];
    const int hrB = history_items[(size_t)b * NT + (actB ? tB : 0)];
    float4 kA[8], kB[8];
    {
        const float4* rpA = (const float4*)(item_table + (size_t)hrA * NE) + half * 8;
        const float4* rpB = (const float4*)(item_table + (size_t)hrB * NE) + half * 8;
#pragma unroll
        for (int i = 0; i < 8; ++i) { kA[i] = rpA[i]; kB[i] = rpB[i]; }
    }

    // ---- stage small shared data ----------------------------------------
    if (tid < NE) sm.q[tid] = item_table[(size_t)target_item[b] * NE + tid];
    for (int i = tid; i < 512; i += 256)
        ((float4*)sm.w2)[i] = ((const float4*)att_w2)[i];
    if (tid < 32) { sm.b2[tid] = att_b2[tid]; sm.wo[tid] = att_wo[tid]; }
    const float bo = att_bo[0];
    __syncthreads();

    // ---- W_eff^T[j][e] + bias partials (thread = (wv, j), 16 e's) -------
    // attn_in = [k, q, k-q, k*q] @ w1 factorizes (q row-constant):
    // h1[j] = relu( sum_e k_e*(w1[e,j]+w1[128+e,j]+q_e*w1[192+e,j])
    //              + b1[j] + sum_e q_e*(w1[64+e,j]-w1[128+e,j]) )
    {
        float pb = 0.f;
        for (int e = wv; e < NE; e += 4) {
            const float qe = sm.q[e];
            const float A  = att_w1[(size_t)(e)       * NE + j];
            const float Bv = att_w1[(size_t)(64 + e)  * NE + j];
            const float C  = att_w1[(size_t)(128 + e) * NE + j];
            const float D  = att_w1[(size_t)(192 + e) * NE + j];
            sm.weffT[j * 72 + e] = A + C + qe * D;
            pb += qe * (Bv - C);
        }
        sm.ip[wv * 64 + j] = pb;
    }
    __syncthreads();
    if (tid < NE)
        sm.biasj[tid] = att_b1[tid] + sm.ip[tid] + sm.ip[64 + tid] +
                        sm.ip[128 + tid] + sm.ip[192 + tid];
    __syncthreads();

    // ---- main loop: each lane does its e-half of both t's ---------------
    float h2A[16], h2B[16];
#pragma unroll
    for (int o = 0; o < 16; ++o) { h2A[o] = 0.f; h2B[o] = 0.f; }

    for (int jj = 0; jj < 64; ++jj) {
        const float4* wrow =
            (const float4*)(sm.weffT + jj * 72 + (half << 5));   // own half
        float aA = 0.f, aB = 0.f;
#pragma unroll
        for (int gi = 0; gi < 8; gi += 2) {          // 2 float4 in flight
            const float4 w0 = wrow[gi + 0];
            const float4 w1 = wrow[gi + 1];
            aA += w0.x * kA[gi + 0].x; aB += w0.x * kB[gi + 0].x;
            aA += w0.y * kA[gi + 0].y; aB += w0.y * kB[gi + 0].y;
            aA += w0.z * kA[gi + 0].z; aB += w0.z * kB[gi + 0].z;
            aA += w0.w * kA[gi + 0].w; aB += w0.w * kB[gi + 0].w;
            aA += w1.x * kA[gi + 1].x; aB += w1.x * kB[gi + 1].x;
            aA += w1.y * kA[gi + 1].y; aB += w1.y * kB[gi + 1].y;
            aA += w1.z * kA[gi + 1].z; aB += w1.z * kB[gi + 1].z;
            aA += w1.w * kA[gi + 1].w; aB += w1.w * kB[gi + 1].w;
        }
        // combine halves within the pair on the VALU pipe (quad-perm DPP)
        aA += dpp_xor1(aA);
        aB += dpp_xor1(aB);
        const float bias = sm.biasj[jj];
        const float h1A = fmaxf(aA + bias, 0.f);
        const float h1B = fmaxf(aB + bias, 0.f);

        const float4* w2row =
            (const float4*)(sm.w2 + jj * 32) + (half << 2);      // own half
#pragma unroll
        for (int o4 = 0; o4 < 4; ++o4) {             // 1 float4 in flight
            const float4 ww = w2row[o4];
            h2A[4 * o4 + 0] += h1A * ww.x;  h2B[4 * o4 + 0] += h1B * ww.x;
            h2A[4 * o4 + 1] += h1A * ww.y;  h2B[4 * o4 + 1] += h1B * ww.y;
            h2A[4 * o4 + 2] += h1A * ww.z;  h2B[4 * o4 + 2] += h1B * ww.z;
            h2A[4 * o4 + 3] += h1A * ww.w;  h2B[4 * o4 + 3] += h1B * ww.w;
        }
    }

    // ---- L3 scores (each lane: own 16-o half, then pair-combine) --------
    float sA = 0.f, sB = 0.f;
#pragma unroll
    for (int o = 0; o < 16; ++o) {
        const float bb  = sm.b2[half * 16 + o];
        const float wwo = sm.wo[half * 16 + o];
        sA += fmaxf(h2A[o] + bb, 0.f) * wwo;
        sB += fmaxf(h2B[o] + bb, 0.f) * wwo;
    }
    sA += dpp_xor1(sA);
    sB += dpp_xor1(sB);
    const float scrA = sA + bo;
    const float scrB = sB + bo;
    const int mkA = history_mask[(size_t)b * NT + tA];
    const int mkB = actB ? history_mask[(size_t)b * NT + tB] : 0;
    const float vA = (mkA != 0) ? scrA : -1e9f;
    const float vB = actB ? ((mkB != 0) ? scrB : -1e9f) : -INFINITY;
    // even lane represents tA, odd lane tB -> each t counted exactly once
    const float v = half ? vB : vA;

    // ---- softmax over 256 slots (4-wave reduce) -------------------------
    float m = v;
#pragma unroll
    for (int s = 32; s; s >>= 1) m = fmaxf(m, __shfl_xor(m, s));
    if (j == 0) sm.red_a[wv] = m;
    __syncthreads();
    const float mx = fmaxf(fmaxf(sm.red_a[0], sm.red_a[1]),
                           fmaxf(sm.red_a[2], sm.red_a[3]));
    const float ex = __expf(v - mx);   // -inf -> 0
    float ssum = ex;
#pragma unroll
    for (int s = 32; s; s >>= 1) ssum += __shfl_xor(ssum, s);
    if (j == 0) sm.red_b[wv] = ssum;
    __syncthreads();
    const float total = sm.red_b[0] + sm.red_b[1] + sm.red_b[2] + sm.red_b[3];
    const float w = ex / total;
    const float wOther = dpp_xor1(w);
    const float wA = half ? wOther : w;
    const float wB = half ? w : wOther;

    // ---- interest: own e-half of both t's, butterfly over 32 pairs ------
#pragma unroll
    for (int i = 0; i < 32; ++i)
        C4(kA, i) = C4(kA, i) * wA + C4(kB, i) * wB;
    BFH(16)
    BFH(8)
    BFH(4)
    BFH(2)
    BFH(1)
    // lane now holds this wave's partial interest for e = half*32 + g
    sm.ip[wv * 64 + half * 32 + g] = kA[0].x;
    __syncthreads();

    // ---- assemble mlp_in row [user, ctx, q, interest, dense] ------------
    float* row = mlp_in + (size_t)b * 272;
    if (tid < NE) {
        const float inter = sm.ip[tid] + sm.ip[64 + tid] +
                            sm.ip[128 + tid] + sm.ip[192 + tid];
        row[0 + tid]   = user_table[(size_t)sparse_features[b * 2 + 0] * NE + tid];
        row[64 + tid]  = ctx_table[(size_t)sparse_features[b * 2 + 1] * NE + tid];
        row[128 + tid] = sm.q[tid];
        row[192 + tid] = inter;
    } else if (tid >= 64 && tid < 80) {
        row[256 + (tid - 64)] = dense_features[(size_t)b * 16 + (tid - 64)];
    }
}

// ---------------------------------------------------------------------------
// Kernel 2: final MLP 272 -> 256 -> 128 -> 1, 4 rows/block (grid 1024,
// 4 blocks/CU) with transposed LDS activations (broadcast b128 reads) and
// unroll-8 load pipelining.
// ---------------------------------------------------------------------------
#define MR 4
__global__ __launch_bounds__(256)
void din_mlp(const float* __restrict__ mlp_in,
             const float* __restrict__ w1,
             const float* __restrict__ b1,
             const float* __restrict__ w2,
             const float* __restrict__ b2,
             const float* __restrict__ ow,
             const float* __restrict__ ob,
             float* __restrict__ out)
{
    __shared__ float inT[272 * MR];     // [k][r]
    __shared__ float h1T[256 * MR];     // [k][r]
    __shared__ float p2[2 * MR * 128];
    __shared__ float h2_lds[MR * 128];

    const int b0  = blockIdx.x * MR;
    const int tid = threadIdx.x;

    // stage transposed: coalesced global read, scattered LDS write
    for (int i = tid; i < MR * 272; i += 256) {
        const int r = i / 272, k = i - 272 * r;
        inT[k * MR + r] = mlp_in[(size_t)b0 * 272 + i];
    }
    __syncthreads();

    // layer 1: 272 -> 256 (thread = col, MR rows via 1 b128 broadcast/k)
    {
        const float bias = b1[tid];
        float a0 = bias, a1 = bias, a2 = bias, a3 = bias;
        const float4* iT = (const float4*)inT;
#pragma unroll 8
        for (int k = 0; k < 272; ++k) {
            const float wv = w1[(size_t)k * 256 + tid];
            const float4 iv = iT[k];
            a0 += iv.x * wv; a1 += iv.y * wv;
            a2 += iv.z * wv; a3 += iv.w * wv;
        }
        float4 o;
        o.x = fmaxf(a0, 0.f); o.y = fmaxf(a1, 0.f);
        o.z = fmaxf(a2, 0.f); o.w = fmaxf(a3, 0.f);
        ((float4*)h1T)[tid] = o;        // h1T[k=tid][r] contiguous
    }
    __syncthreads();

    // layer 2: 256 -> 128, split-K over two half-blocks
    {
        const int o = tid & 127, half = tid >> 7;
        float c0 = 0.f, c1 = 0.f, c2 = 0.f, c3 = 0.f;
        const float4* hT = (const float4*)h1T;
#pragma unroll 8
        for (int kk = 0; kk < 128; ++kk) {
            const int k = half * 128 + kk;
            const float wv = w2[(size_t)k * 128 + o];
            const float4 hv = hT[k];
            c0 += hv.x * wv; c1 += hv.y * wv;
            c2 += hv.z * wv; c3 += hv.w * wv;
        }
        p2[(half * MR + 0) * 128 + o] = c0;
        p2[(half * MR + 1) * 128 + o] = c1;
        p2[(half * MR + 2) * 128 + o] = c2;
        p2[(half * MR + 3) * 128 + o] = c3;
    }
    __syncthreads();
    if (tid < 128) {
        const float bias = b2[tid];
#pragma unroll
        for (int r = 0; r < MR; ++r)
            h2_lds[r * 128 + tid] =
                fmaxf(p2[r * 128 + tid] + p2[(MR + r) * 128 + tid] + bias, 0.f);
    }
    __syncthreads();

    // layer 3: 128 -> 1 (16 lanes per row)
    if (tid < 16 * MR) {
        const int r = tid >> 4, l = tid & 15;
        float a = 0.f;
#pragma unroll
        for (int kk = 0; kk < 8; ++kk) {
            const int k = l * 8 + kk;
            a += h2_lds[r * 128 + k] * ow[k];
        }
        a += __shfl_xor(a, 8, 16);
        a += __shfl_xor(a, 4, 16);
        a += __shfl_xor(a, 2, 16);
        a += __shfl_xor(a, 1, 16);
        if (l == 0) out[b0 + r] = a + ob[0];
    }
}

// ---------------------------------------------------------------------------
extern "C" void kernel_launch(void* const* d_in, const int* in_sizes, int n_in,
                              void* d_out, int out_size, void* d_ws, size_t ws_size,
                              hipStream_t stream)
{
    float* mlp_in = (float*)d_ws;   // 4096*272*4 = 4.46 MB

    din_attn<<<NB, 256, 0, stream>>>(
        (const int*)d_in[0],      // target_item
        (const int*)d_in[1],      // history_items
        (const int*)d_in[2],      // history_mask
        (const int*)d_in[3],      // sparse_features
        (const float*)d_in[4],    // dense_features
        (const float*)d_in[5],    // item_table
        (const float*)d_in[6],    // user_table
        (const float*)d_in[7],    // ctx_table
        (const float*)d_in[8],  (const float*)d_in[9],   // att_w1, att_b1
        (const float*)d_in[10], (const float*)d_in[11],  // att_w2, att_b2
        (const float*)d_in[12], (const float*)d_in[13],  // att_wo, att_bo
        mlp_in);

    din_mlp<<<NB / MR, 256, 0, stream>>>(
        mlp_in,
        (const float*)d_in[14], (const float*)d_in[15],  // mlp_w1, mlp_b1
        (const float*)d_in[16], (const float*)d_in[17],  // mlp_w2, mlp_b2
        (const float*)d_in[18], (const float*)d_in[19],  // out_w, out_b
        (float*)d_out);
}